// Round 2
// baseline (54.832 us; speedup 1.0000x reference)
//
#include <hip/hip_runtime.h>

#define HWE 131072   // 256*512 env pixels
#define OPIX 16384   // 128*128 output pixels

// Pack per env pixel: [x0.rgb, y0.rgb, (x1-y1).rgb, (x2-y2).rgb, (x3-y3).rgb, pad]
// -> 16 floats = 64B = one cache line per gather position.
// 4 pixels per thread, float4 reads (12 floats = 3 float4 per (b, 4pix)).
__global__ __launch_bounds__(256) void k_repack4(
    const float* __restrict__ x, const float* __restrict__ y,
    float* __restrict__ env) {
  int t = blockIdx.x * 256 + threadIdx.x;
  int pix0 = t * 4;
  float xs[4][12], ys_[4][12];   // [b][4px*3c]
  #pragma unroll
  for (int b = 0; b < 4; b++) {
    const float4* xp = (const float4*)(x + ((size_t)b * HWE + pix0) * 3);
    const float4* yp = (const float4*)(y + ((size_t)b * HWE + pix0) * 3);
    float4 a0 = xp[0], a1 = xp[1], a2 = xp[2];
    float4 b0 = yp[0], b1 = yp[1], b2 = yp[2];
    float* xd = xs[b]; float* yd = ys_[b];
    xd[0]=a0.x; xd[1]=a0.y; xd[2]=a0.z; xd[3]=a0.w; xd[4]=a1.x; xd[5]=a1.y;
    xd[6]=a1.z; xd[7]=a1.w; xd[8]=a2.x; xd[9]=a2.y; xd[10]=a2.z; xd[11]=a2.w;
    yd[0]=b0.x; yd[1]=b0.y; yd[2]=b0.z; yd[3]=b0.w; yd[4]=b1.x; yd[5]=b1.y;
    yd[6]=b1.z; yd[7]=b1.w; yd[8]=b2.x; yd[9]=b2.y; yd[10]=b2.z; yd[11]=b2.w;
  }
  #pragma unroll
  for (int p = 0; p < 4; p++) {
    float o[16];
    #pragma unroll
    for (int c = 0; c < 3; c++) {
      o[c]     = xs[0][p * 3 + c];
      o[3 + c] = ys_[0][p * 3 + c];
      o[6 + c]  = xs[1][p * 3 + c] - ys_[1][p * 3 + c];
      o[9 + c]  = xs[2][p * 3 + c] - ys_[2][p * 3 + c];
      o[12 + c] = xs[3][p * 3 + c] - ys_[3][p * 3 + c];
    }
    o[15] = 0.f;
    float4* dst = (float4*)(env + (size_t)(pix0 + p) * 16);
    dst[0] = make_float4(o[0],  o[1],  o[2],  o[3]);
    dst[1] = make_float4(o[4],  o[5],  o[6],  o[7]);
    dst[2] = make_float4(o[8],  o[9],  o[10], o[11]);
    dst[3] = make_float4(o[12], o[13], o[14], o[15]);
  }
}

// Fused render + cross-group reduce + outputs + per-block loss partial.
// Block = 256 threads = 8 groups x 32 output pixels. Grid = OPIX/32 = 512.
// Group g: pass = g>>2, n in [(g&3)*8, (g&3)*8+8).
#define SLAB 516           // 32*16 + 4 pad words: g-stride banks differ by 4
__global__ __launch_bounds__(256) void k_render_fused(
    const float* __restrict__ bs0, const float* __restrict__ bd0,
    const int* __restrict__ ix0, const int* __restrict__ iy0,
    const float* __restrict__ w0,
    const float* __restrict__ bs1, const float* __restrict__ bd1,
    const int* __restrict__ ix1, const int* __restrict__ iy1,
    const float* __restrict__ w1,
    const float* __restrict__ env, float* __restrict__ d_out,
    float* __restrict__ loss_part) {
  int tid = threadIdx.x;
  int g = tid >> 5;
  int opl = tid & 31;
  int opix = blockIdx.x * 32 + opl;

  const float* bs; const float* bd; const int* ix; const int* iy; const float* w;
  if (g < 4) { bs = bs0; bd = bd0; ix = ix0; iy = iy0; w = w0; }
  else       { bs = bs1; bd = bd1; ix = ix1; iy = iy1; w = w1; }
  int n0 = (g & 3) * 8;

  float acc[16];
  #pragma unroll
  for (int j = 0; j < 16; j++) acc[j] = 0.f;

  #pragma unroll
  for (int k = 0; k < 8; k++) {
    int n = n0 + k;
    int off = n * OPIX + opix;
    float coef = (bd[off] + 10.0f * bs[off]) * w[n];
    int gp = iy[off] * 512 + ix[off];
    const float4* e = (const float4*)(env + (size_t)gp * 16);
    float4 e0 = e[0], e1 = e[1], e2 = e[2], e3 = e[3];
    acc[0]  = fmaf(coef, e0.x, acc[0]);
    acc[1]  = fmaf(coef, e0.y, acc[1]);
    acc[2]  = fmaf(coef, e0.z, acc[2]);
    acc[3]  = fmaf(coef, e0.w, acc[3]);
    acc[4]  = fmaf(coef, e1.x, acc[4]);
    acc[5]  = fmaf(coef, e1.y, acc[5]);
    acc[6]  = fmaf(coef, e1.z, acc[6]);
    acc[7]  = fmaf(coef, e1.w, acc[7]);
    acc[8]  = fmaf(coef, e2.x, acc[8]);
    acc[9]  = fmaf(coef, e2.y, acc[9]);
    acc[10] = fmaf(coef, e2.z, acc[10]);
    acc[11] = fmaf(coef, e2.w, acc[11]);
    acc[12] = fmaf(coef, e3.x, acc[12]);
    acc[13] = fmaf(coef, e3.y, acc[13]);
    acc[14] = fmaf(coef, e3.z, acc[14]);
    acc[15] = fmaf(coef, e3.w, acc[15]);
  }

  __shared__ float sm[8 * SLAB];     // 16.5 KB
  __shared__ float fin[32 * 17];     // 2.2 KB, 17 coprime 32 -> conflict-free
  {
    float4* my = (float4*)&sm[g * SLAB + opl * 16];
    my[0] = make_float4(acc[0],  acc[1],  acc[2],  acc[3]);
    my[1] = make_float4(acc[4],  acc[5],  acc[6],  acc[7]);
    my[2] = make_float4(acc[8],  acc[9],  acc[10], acc[11]);
    my[3] = make_float4(acc[12], acc[13], acc[14], acc[15]);
  }
  __syncthreads();

  // cross-group sum: thread -> (opl2 = tid>>3, components 2*(tid&7), +1)
  int opl2 = tid >> 3;
  int cp = (tid & 7) * 2;
  float s0 = 0.f, s1 = 0.f;
  #pragma unroll
  for (int g2 = 0; g2 < 8; g2++) {
    float2 v = *(const float2*)&sm[g2 * SLAB + opl2 * 16 + cp];
    s0 += v.x; s1 += v.y;
  }
  fin[opl2 * 17 + cp]     = s0;
  fin[opl2 * 17 + cp + 1] = s1;
  __syncthreads();

  if (tid < 32) {
    float a[15];
    #pragma unroll
    for (int c = 0; c < 15; c++) a[c] = fin[tid * 17 + c];
    int op = blockIdx.x * 32 + tid;
    float l = 0.f;
    #pragma unroll
    for (int c = 0; c < 3; c++) {
      d_out[1 + c * OPIX + op]       = a[c];       // pred[0]
      d_out[1 + (3 + c) * OPIX + op] = a[3 + c];   // gt[0]
      float d0 = a[c] - a[3 + c];
      l += d0 * d0 + a[6 + c] * a[6 + c] + a[9 + c] * a[9 + c]
         + a[12 + c] * a[12 + c];
    }
    // deterministic 32-lane down-reduce (lanes 0..31 of wave 0)
    #pragma unroll
    for (int s = 16; s > 0; s >>= 1) l += __shfl_down(l, s);
    if (tid == 0) loss_part[blockIdx.x] = l;
  }
}

// Deterministic final reduction of 512 block partials (no atomics).
__global__ __launch_bounds__(256) void k_loss(
    const float* __restrict__ loss_part, float* __restrict__ d_out) {
  int tid = threadIdx.x;
  float v = loss_part[tid] + loss_part[tid + 256];
  #pragma unroll
  for (int s = 32; s > 0; s >>= 1) v += __shfl_down(v, s, 64);
  __shared__ float red[4];
  int lane = tid & 63, wid = tid >> 6;
  if (lane == 0) red[wid] = v;
  __syncthreads();
  if (tid == 0)
    d_out[0] = (red[0] + red[1] + red[2] + red[3]) * (1.0f / 98304.0f);
}

extern "C" void kernel_launch(void* const* d_in, const int* in_sizes, int n_in,
                              void* d_out, int out_size, void* d_ws, size_t ws_size,
                              hipStream_t stream) {
  const float* x   = (const float*)d_in[0];
  const float* y   = (const float*)d_in[1];
  const float* bs0 = (const float*)d_in[2];
  const float* bd0 = (const float*)d_in[3];
  const int*   ix0 = (const int*)  d_in[4];
  const int*   iy0 = (const int*)  d_in[5];
  const float* w0  = (const float*)d_in[6];
  const float* bs1 = (const float*)d_in[7];
  const float* bd1 = (const float*)d_in[8];
  const int*   ix1 = (const int*)  d_in[9];
  const int*   iy1 = (const int*)  d_in[10];
  const float* w1  = (const float*)d_in[11];
  float* out = (float*)d_out;

  float* env       = (float*)d_ws;             // 131072*16 f32 = 8 MB
  float* loss_part = env + (size_t)HWE * 16;   // 512 f32

  hipLaunchKernelGGL(k_repack4, dim3(HWE / 4 / 256), dim3(256), 0, stream,
                     x, y, env);
  hipLaunchKernelGGL(k_render_fused, dim3(OPIX / 32), dim3(256), 0, stream,
                     bs0, bd0, ix0, iy0, w0, bs1, bd1, ix1, iy1, w1,
                     env, out, loss_part);
  hipLaunchKernelGGL(k_loss, dim3(1), dim3(256), 0, stream, loss_part, out);
}

// Round 3
// 30.601 us; speedup vs baseline: 1.7919x; 1.7919x over previous
//
#include <hip/hip_runtime.h>
#include <hip/hip_fp16.h>

#define HWE 131072   // 256*512 env pixels
#define OPIX 16384   // 128*128 output pixels

__device__ __forceinline__ unsigned pack2(float a, float b) {
  __half2 h = __floats2half2_rn(a, b);
  return *(unsigned*)&h;
}

// Pack per env pixel (fp16): [x0.rgb, y0.rgb, d1.rgb, d2.rgb, d3.rgb, pad]
// = 16 halves = 32 B = half a cache line. env total = 4 MB -> L2-resident.
__global__ __launch_bounds__(256) void k_repack4(
    const float* __restrict__ x, const float* __restrict__ y,
    uint4* __restrict__ env) {
  int t = blockIdx.x * 256 + threadIdx.x;
  int pix0 = t * 4;
  float xs[4][12], ys_[4][12];   // [b][4px*3c]
  #pragma unroll
  for (int b = 0; b < 4; b++) {
    const float4* xp = (const float4*)(x + ((size_t)b * HWE + pix0) * 3);
    const float4* yp = (const float4*)(y + ((size_t)b * HWE + pix0) * 3);
    float4 a0 = xp[0], a1 = xp[1], a2 = xp[2];
    float4 b0 = yp[0], b1 = yp[1], b2 = yp[2];
    float* xd = xs[b]; float* yd = ys_[b];
    xd[0]=a0.x; xd[1]=a0.y; xd[2]=a0.z; xd[3]=a0.w; xd[4]=a1.x; xd[5]=a1.y;
    xd[6]=a1.z; xd[7]=a1.w; xd[8]=a2.x; xd[9]=a2.y; xd[10]=a2.z; xd[11]=a2.w;
    yd[0]=b0.x; yd[1]=b0.y; yd[2]=b0.z; yd[3]=b0.w; yd[4]=b1.x; yd[5]=b1.y;
    yd[6]=b1.z; yd[7]=b1.w; yd[8]=b2.x; yd[9]=b2.y; yd[10]=b2.z; yd[11]=b2.w;
  }
  #pragma unroll
  for (int p = 0; p < 4; p++) {
    float o[15];
    #pragma unroll
    for (int c = 0; c < 3; c++) {
      o[c]      = xs[0][p * 3 + c];
      o[3 + c]  = ys_[0][p * 3 + c];
      o[6 + c]  = xs[1][p * 3 + c] - ys_[1][p * 3 + c];
      o[9 + c]  = xs[2][p * 3 + c] - ys_[2][p * 3 + c];
      o[12 + c] = xs[3][p * 3 + c] - ys_[3][p * 3 + c];
    }
    uint4 q0, q1;
    q0.x = pack2(o[0],  o[1]);
    q0.y = pack2(o[2],  o[3]);
    q0.z = pack2(o[4],  o[5]);
    q0.w = pack2(o[6],  o[7]);
    q1.x = pack2(o[8],  o[9]);
    q1.y = pack2(o[10], o[11]);
    q1.z = pack2(o[12], o[13]);
    q1.w = pack2(o[14], 0.f);
    env[(size_t)(pix0 + p) * 2 + 0] = q0;
    env[(size_t)(pix0 + p) * 2 + 1] = q1;
  }
}

// Fused render + cross-group reduce + outputs + per-block loss partial.
// Block = 256 threads = 8 groups x 32 output pixels. Grid = OPIX/32 = 512.
#define SLAB 516           // 32*16 + 4 pad words
__global__ __launch_bounds__(256) void k_render_fused(
    const float* __restrict__ bs0, const float* __restrict__ bd0,
    const int* __restrict__ ix0, const int* __restrict__ iy0,
    const float* __restrict__ w0,
    const float* __restrict__ bs1, const float* __restrict__ bd1,
    const int* __restrict__ ix1, const int* __restrict__ iy1,
    const float* __restrict__ w1,
    const uint4* __restrict__ env, float* __restrict__ d_out,
    float* __restrict__ loss_part) {
  int tid = threadIdx.x;
  int g = tid >> 5;
  int opl = tid & 31;
  int opix = blockIdx.x * 32 + opl;

  const float* bs; const float* bd; const int* ix; const int* iy; const float* w;
  if (g < 4) { bs = bs0; bd = bd0; ix = ix0; iy = iy0; w = w0; }
  else       { bs = bs1; bd = bd1; ix = ix1; iy = iy1; w = w1; }
  int n0 = (g & 3) * 8;

  float acc[15];
  #pragma unroll
  for (int j = 0; j < 15; j++) acc[j] = 0.f;

  #pragma unroll
  for (int k = 0; k < 8; k++) {
    int n = n0 + k;
    int off = n * OPIX + opix;
    float coef = (bd[off] + 10.0f * bs[off]) * w[n];
    int gp = iy[off] * 512 + ix[off];
    uint4 q0 = env[(size_t)gp * 2 + 0];
    uint4 q1 = env[(size_t)gp * 2 + 1];
    float2 v;
    v = __half22float2(*(__half2*)&q0.x); acc[0]  = fmaf(coef, v.x, acc[0]);  acc[1]  = fmaf(coef, v.y, acc[1]);
    v = __half22float2(*(__half2*)&q0.y); acc[2]  = fmaf(coef, v.x, acc[2]);  acc[3]  = fmaf(coef, v.y, acc[3]);
    v = __half22float2(*(__half2*)&q0.z); acc[4]  = fmaf(coef, v.x, acc[4]);  acc[5]  = fmaf(coef, v.y, acc[5]);
    v = __half22float2(*(__half2*)&q0.w); acc[6]  = fmaf(coef, v.x, acc[6]);  acc[7]  = fmaf(coef, v.y, acc[7]);
    v = __half22float2(*(__half2*)&q1.x); acc[8]  = fmaf(coef, v.x, acc[8]);  acc[9]  = fmaf(coef, v.y, acc[9]);
    v = __half22float2(*(__half2*)&q1.y); acc[10] = fmaf(coef, v.x, acc[10]); acc[11] = fmaf(coef, v.y, acc[11]);
    v = __half22float2(*(__half2*)&q1.z); acc[12] = fmaf(coef, v.x, acc[12]); acc[13] = fmaf(coef, v.y, acc[13]);
    v = __half22float2(*(__half2*)&q1.w); acc[14] = fmaf(coef, v.x, acc[14]);
  }

  __shared__ float sm[8 * SLAB];     // 16.5 KB
  __shared__ float fin[32 * 17];     // 2.2 KB
  {
    float4* my = (float4*)&sm[g * SLAB + opl * 16];
    my[0] = make_float4(acc[0],  acc[1],  acc[2],  acc[3]);
    my[1] = make_float4(acc[4],  acc[5],  acc[6],  acc[7]);
    my[2] = make_float4(acc[8],  acc[9],  acc[10], acc[11]);
    my[3] = make_float4(acc[12], acc[13], acc[14], 0.f);
  }
  __syncthreads();

  // cross-group sum: thread -> (opl2 = tid>>3, components 2*(tid&7), +1)
  int opl2 = tid >> 3;
  int cp = (tid & 7) * 2;
  float s0 = 0.f, s1 = 0.f;
  #pragma unroll
  for (int g2 = 0; g2 < 8; g2++) {
    float2 v = *(const float2*)&sm[g2 * SLAB + opl2 * 16 + cp];
    s0 += v.x; s1 += v.y;
  }
  fin[opl2 * 17 + cp]     = s0;
  fin[opl2 * 17 + cp + 1] = s1;
  __syncthreads();

  if (tid < 32) {
    float a[15];
    #pragma unroll
    for (int c = 0; c < 15; c++) a[c] = fin[tid * 17 + c];
    int op = blockIdx.x * 32 + tid;
    float l = 0.f;
    #pragma unroll
    for (int c = 0; c < 3; c++) {
      d_out[1 + c * OPIX + op]       = a[c];       // pred[0]
      d_out[1 + (3 + c) * OPIX + op] = a[3 + c];   // gt[0]
      float d0 = a[c] - a[3 + c];
      l += d0 * d0 + a[6 + c] * a[6 + c] + a[9 + c] * a[9 + c]
         + a[12 + c] * a[12 + c];
    }
    #pragma unroll
    for (int s = 16; s > 0; s >>= 1) l += __shfl_down(l, s);
    if (tid == 0) loss_part[blockIdx.x] = l;
  }
}

// Deterministic final reduction of 512 block partials (no atomics).
__global__ __launch_bounds__(256) void k_loss(
    const float* __restrict__ loss_part, float* __restrict__ d_out) {
  int tid = threadIdx.x;
  float v = loss_part[tid] + loss_part[tid + 256];
  #pragma unroll
  for (int s = 32; s > 0; s >>= 1) v += __shfl_down(v, s, 64);
  __shared__ float red[4];
  int lane = tid & 63, wid = tid >> 6;
  if (lane == 0) red[wid] = v;
  __syncthreads();
  if (tid == 0)
    d_out[0] = (red[0] + red[1] + red[2] + red[3]) * (1.0f / 98304.0f);
}

extern "C" void kernel_launch(void* const* d_in, const int* in_sizes, int n_in,
                              void* d_out, int out_size, void* d_ws, size_t ws_size,
                              hipStream_t stream) {
  const float* x   = (const float*)d_in[0];
  const float* y   = (const float*)d_in[1];
  const float* bs0 = (const float*)d_in[2];
  const float* bd0 = (const float*)d_in[3];
  const int*   ix0 = (const int*)  d_in[4];
  const int*   iy0 = (const int*)  d_in[5];
  const float* w0  = (const float*)d_in[6];
  const float* bs1 = (const float*)d_in[7];
  const float* bd1 = (const float*)d_in[8];
  const int*   ix1 = (const int*)  d_in[9];
  const int*   iy1 = (const int*)  d_in[10];
  const float* w1  = (const float*)d_in[11];
  float* out = (float*)d_out;

  uint4* env       = (uint4*)d_ws;                        // 131072*32 B = 4 MB
  float* loss_part = (float*)((char*)d_ws + (size_t)HWE * 32); // 512 f32

  hipLaunchKernelGGL(k_repack4, dim3(HWE / 4 / 256), dim3(256), 0, stream,
                     x, y, env);
  hipLaunchKernelGGL(k_render_fused, dim3(OPIX / 32), dim3(256), 0, stream,
                     bs0, bd0, ix0, iy0, w0, bs1, bd1, ix1, iy1, w1,
                     env, out, loss_part);
  hipLaunchKernelGGL(k_loss, dim3(1), dim3(256), 0, stream, loss_part, out);
}

// Round 4
// 21.087 us; speedup vs baseline: 2.6003x; 1.4512x over previous
//
#include <hip/hip_runtime.h>

#define HWE 131072   // 256*512 env pixels
#define OPIX 16384   // 128*128 output pixels

typedef float f32x2 __attribute__((ext_vector_type(2)));

// Pack per env pixel (fp8 e4m3, HW convert): [x0.rgb, y0.rgb, d1.rgb, d2.rgb,
// d3.rgb, pad] = 16 bytes. env total = 2 MB -> solidly L2-resident.
// One pixel per thread -> 512 blocks (full-device streaming BW).
__global__ __launch_bounds__(256) void k_repack1(
    const float* __restrict__ x, const float* __restrict__ y,
    uint4* __restrict__ env) {
  int px = blockIdx.x * 256 + threadIdx.x;
  float o[16];
  #pragma unroll
  for (int c = 0; c < 3; c++) {
    float x0 = x[(size_t)px * 3 + c];
    float y0 = y[(size_t)px * 3 + c];
    o[c]     = x0;
    o[3 + c] = y0;
    #pragma unroll
    for (int b = 1; b < 4; b++) {
      float xv = x[((size_t)b * HWE + px) * 3 + c];
      float yv = y[((size_t)b * HWE + px) * 3 + c];
      o[3 + b * 3 + c] = xv - yv;
    }
  }
  o[15] = 0.f;
  uint4 q;
  q.x = (unsigned)__builtin_amdgcn_cvt_pk_fp8_f32(o[2],  o[3],
        __builtin_amdgcn_cvt_pk_fp8_f32(o[0],  o[1],  0, false), true);
  q.y = (unsigned)__builtin_amdgcn_cvt_pk_fp8_f32(o[6],  o[7],
        __builtin_amdgcn_cvt_pk_fp8_f32(o[4],  o[5],  0, false), true);
  q.z = (unsigned)__builtin_amdgcn_cvt_pk_fp8_f32(o[10], o[11],
        __builtin_amdgcn_cvt_pk_fp8_f32(o[8],  o[9],  0, false), true);
  q.w = (unsigned)__builtin_amdgcn_cvt_pk_fp8_f32(o[14], o[15],
        __builtin_amdgcn_cvt_pk_fp8_f32(o[12], o[13], 0, false), true);
  env[px] = q;
}

// Fused render + cross-group reduce + outputs + per-block loss partial.
// Block = 512 threads = 16 groups x 32 output pixels; 4 n's per group.
// Grid = OPIX/32 = 512 -> 4096 waves (16/CU) for gather latency hiding.
#define SLAB 516           // 32*16 + 4 pad words
__global__ __launch_bounds__(512) void k_render_fused(
    const float* __restrict__ bs0, const float* __restrict__ bd0,
    const int* __restrict__ ix0, const int* __restrict__ iy0,
    const float* __restrict__ w0,
    const float* __restrict__ bs1, const float* __restrict__ bd1,
    const int* __restrict__ ix1, const int* __restrict__ iy1,
    const float* __restrict__ w1,
    const uint4* __restrict__ env, float* __restrict__ d_out,
    float* __restrict__ loss_part) {
  int tid = threadIdx.x;
  int g = tid >> 5;          // 0..15
  int opl = tid & 31;
  int opix = blockIdx.x * 32 + opl;

  const float* bs; const float* bd; const int* ix; const int* iy; const float* w;
  if (g < 8) { bs = bs0; bd = bd0; ix = ix0; iy = iy0; w = w0; }
  else       { bs = bs1; bd = bd1; ix = ix1; iy = iy1; w = w1; }
  int n0 = (g & 7) * 4;

  float acc[15];
  #pragma unroll
  for (int j = 0; j < 15; j++) acc[j] = 0.f;

  #pragma unroll
  for (int k = 0; k < 4; k++) {
    int n = n0 + k;
    int off = n * OPIX + opix;
    float coef = (bd[off] + 10.0f * bs[off]) * w[n];
    int gp = iy[off] * 512 + ix[off];
    uint4 q = env[gp];
    f32x2 v;
    v = __builtin_amdgcn_cvt_pk_f32_fp8(q.x, false); acc[0]  = fmaf(coef, v.x, acc[0]);  acc[1]  = fmaf(coef, v.y, acc[1]);
    v = __builtin_amdgcn_cvt_pk_f32_fp8(q.x, true);  acc[2]  = fmaf(coef, v.x, acc[2]);  acc[3]  = fmaf(coef, v.y, acc[3]);
    v = __builtin_amdgcn_cvt_pk_f32_fp8(q.y, false); acc[4]  = fmaf(coef, v.x, acc[4]);  acc[5]  = fmaf(coef, v.y, acc[5]);
    v = __builtin_amdgcn_cvt_pk_f32_fp8(q.y, true);  acc[6]  = fmaf(coef, v.x, acc[6]);  acc[7]  = fmaf(coef, v.y, acc[7]);
    v = __builtin_amdgcn_cvt_pk_f32_fp8(q.z, false); acc[8]  = fmaf(coef, v.x, acc[8]);  acc[9]  = fmaf(coef, v.y, acc[9]);
    v = __builtin_amdgcn_cvt_pk_f32_fp8(q.z, true);  acc[10] = fmaf(coef, v.x, acc[10]); acc[11] = fmaf(coef, v.y, acc[11]);
    v = __builtin_amdgcn_cvt_pk_f32_fp8(q.w, false); acc[12] = fmaf(coef, v.x, acc[12]); acc[13] = fmaf(coef, v.y, acc[13]);
    v = __builtin_amdgcn_cvt_pk_f32_fp8(q.w, true);  acc[14] = fmaf(coef, v.x, acc[14]);
  }

  __shared__ float sm[16 * SLAB];    // 33 KB
  __shared__ float fin[32 * 17];     // 2.2 KB
  {
    float4* my = (float4*)&sm[g * SLAB + opl * 16];
    my[0] = make_float4(acc[0],  acc[1],  acc[2],  acc[3]);
    my[1] = make_float4(acc[4],  acc[5],  acc[6],  acc[7]);
    my[2] = make_float4(acc[8],  acc[9],  acc[10], acc[11]);
    my[3] = make_float4(acc[12], acc[13], acc[14], 0.f);
  }
  __syncthreads();

  // cross-group sum: thread -> (opl2 = tid>>4, component tid&15)
  {
    int opl2 = tid >> 4;
    int cp = tid & 15;
    float s = 0.f;
    #pragma unroll
    for (int g2 = 0; g2 < 16; g2++)
      s += sm[g2 * SLAB + opl2 * 16 + cp];
    fin[opl2 * 17 + cp] = s;
  }
  __syncthreads();

  if (tid < 32) {
    float a[15];
    #pragma unroll
    for (int c = 0; c < 15; c++) a[c] = fin[tid * 17 + c];
    int op = blockIdx.x * 32 + tid;
    float l = 0.f;
    #pragma unroll
    for (int c = 0; c < 3; c++) {
      d_out[1 + c * OPIX + op]       = a[c];       // pred[0]
      d_out[1 + (3 + c) * OPIX + op] = a[3 + c];   // gt[0]
      float d0 = a[c] - a[3 + c];
      l += d0 * d0 + a[6 + c] * a[6 + c] + a[9 + c] * a[9 + c]
         + a[12 + c] * a[12 + c];
    }
    #pragma unroll
    for (int s = 16; s > 0; s >>= 1) l += __shfl_down(l, s);
    if (tid == 0) loss_part[blockIdx.x] = l;
  }
}

// Deterministic final reduction of 512 block partials (no atomics).
__global__ __launch_bounds__(256) void k_loss(
    const float* __restrict__ loss_part, float* __restrict__ d_out) {
  int tid = threadIdx.x;
  float v = loss_part[tid] + loss_part[tid + 256];
  #pragma unroll
  for (int s = 32; s > 0; s >>= 1) v += __shfl_down(v, s, 64);
  __shared__ float red[4];
  int lane = tid & 63, wid = tid >> 6;
  if (lane == 0) red[wid] = v;
  __syncthreads();
  if (tid == 0)
    d_out[0] = (red[0] + red[1] + red[2] + red[3]) * (1.0f / 98304.0f);
}

extern "C" void kernel_launch(void* const* d_in, const int* in_sizes, int n_in,
                              void* d_out, int out_size, void* d_ws, size_t ws_size,
                              hipStream_t stream) {
  const float* x   = (const float*)d_in[0];
  const float* y   = (const float*)d_in[1];
  const float* bs0 = (const float*)d_in[2];
  const float* bd0 = (const float*)d_in[3];
  const int*   ix0 = (const int*)  d_in[4];
  const int*   iy0 = (const int*)  d_in[5];
  const float* w0  = (const float*)d_in[6];
  const float* bs1 = (const float*)d_in[7];
  const float* bd1 = (const float*)d_in[8];
  const int*   ix1 = (const int*)  d_in[9];
  const int*   iy1 = (const int*)  d_in[10];
  const float* w1  = (const float*)d_in[11];
  float* out = (float*)d_out;

  uint4* env       = (uint4*)d_ws;                             // 2 MB
  float* loss_part = (float*)((char*)d_ws + (size_t)HWE * 16); // 512 f32

  hipLaunchKernelGGL(k_repack1, dim3(HWE / 256), dim3(256), 0, stream,
                     x, y, env);
  hipLaunchKernelGGL(k_render_fused, dim3(OPIX / 32), dim3(512), 0, stream,
                     bs0, bd0, ix0, iy0, w0, bs1, bd1, ix1, iy1, w1,
                     env, out, loss_part);
  hipLaunchKernelGGL(k_loss, dim3(1), dim3(256), 0, stream, loss_part, out);
}